// Round 1
// baseline (94.807 us; speedup 1.0000x reference)
//
#include <hip/hip_runtime.h>

#define THREADS 512
#define NBLK 1024  // 65536 rows / 64 per block

typedef _Float16 half8 __attribute__((ext_vector_type(8)));
typedef float floatx4 __attribute__((ext_vector_type(4)));

__device__ __forceinline__ unsigned int f2h(float f) {
  union { _Float16 h; unsigned short u; } v;
  v.h = (_Float16)f;  // RNE
  return (unsigned int)v.u;
}

// --- Kernel 1: W [512(k)][512(n)] fp32 -> Wt [512(n)][512(k)] f16 ---
__global__ void wcvt_kernel(const float* __restrict__ W, unsigned short* __restrict__ Wt) {
  __shared__ float tile[32][33];
  const int tx = threadIdx.x, ty = threadIdx.y;
  const int nb = blockIdx.x * 32, kb = blockIdx.y * 32;
#pragma unroll
  for (int i = 0; i < 4; ++i)
    tile[ty + 8 * i][tx] = W[(size_t)(kb + ty + 8 * i) * 512 + nb + tx];
  __syncthreads();
#pragma unroll
  for (int i = 0; i < 4; ++i) {
    union { _Float16 h; unsigned short u; } v;
    v.h = (_Float16)tile[tx][ty + 8 * i];
    Wt[(size_t)(nb + ty + 8 * i) * 512 + kb + tx] = v.u;
  }
}

// --- Kernel 2: fused GEMM + surrogate-sigmoid + rowwise LayerNorm ---
// Block: 64 rows x 512 cols. 8 waves = 2 (row) x 4 (col), wave tile 32x128.
// LDS layout (bytes):
//   [0, 65536)      : B buffers, 2 x (32k x 512n f16, XOR-swizzled 16B slots)
//   [65536, 73728)  : A buffers, 2 x (64r x 32k f16, XOR-swizzled)
//   [73728, 74752)  : redS [64][4]
//   [74752, 75776)  : redQ [64][4]
//   [75776, 76288)  : mv   [64][2]
__global__ __launch_bounds__(THREADS, 4) void lif_fused_kernel(
    const float* __restrict__ A, const unsigned short* __restrict__ Wt,
    const float* __restrict__ bias, const float* __restrict__ lnw,
    const float* __restrict__ lnb, float* __restrict__ out) {
  __shared__ uint4 smem4[4768];  // 76288 bytes
  unsigned char* smem = (unsigned char*)smem4;

  const int tid  = threadIdx.x;
  const int lane = tid & 63;
  const int wave = tid >> 6;
  const int wrow = wave >> 2;  // 0..1
  const int wcol = wave & 3;   // 0..3
  const int l15  = lane & 15;
  const int g    = lane >> 4;  // 0..3
  const int rowBase = blockIdx.x * 64;

  // A staging: thread t loads A[row=t/8][kloc=(t%8)*4 .. +4) fp32, writes 8B f16 to LDS
  const int arow  = tid >> 3;
  const int akloc = (tid & 7) << 2;
  const int aWriteOff = 65536 + arow * 64 +
                        (((akloc >> 3) ^ ((arow >> 1) & 3)) << 4) + ((akloc & 7) << 1);
  const size_t aSrcBase = (size_t)(rowBase + arow) * 512 + akloc;

  // Fragment read swizzle: slot' = g ^ ((row>>1)&3); row%2-independent bits fold to l15
  const int sw = ((g ^ ((l15 >> 1) & 3)) << 4);
  const int aReadBase = 65536 + (wrow * 32 + l15) * 64 + sw;  // + bb*4096 + m*1024
  const int bReadBase = (wcol * 128 + l15) * 64 + sw;         // + bb*32768 + n*1024

  auto stageB = [&](int bb, int kk) {
#pragma unroll
    for (int i = 0; i < 4; ++i) {
      const int n = i * 128 + (tid >> 2);
      const int slot = (tid & 3) ^ ((n >> 1) & 3);  // inverse-swizzled global source
      const unsigned short* src = Wt + n * 512 + kk * 32 + slot * 8;
      int off = bb * 32768 + i * 8192 + wave * 1024;  // wave-uniform linear LDS dest
      off = __builtin_amdgcn_readfirstlane(off);
      __builtin_amdgcn_global_load_lds(
          (const __attribute__((address_space(1))) void*)src,
          (__attribute__((address_space(3))) void*)(smem + off), 16, 0, 0);
    }
  };

  floatx4 acc[2][8];
#pragma unroll
  for (int m = 0; m < 2; ++m)
#pragma unroll
    for (int n = 0; n < 8; ++n)
      acc[m][n] = (floatx4){0.f, 0.f, 0.f, 0.f};

  // Prologue: stage K-step 0 into buffer 0
  stageB(0, 0);
  {
    float4 v = *(const float4*)(A + aSrcBase);
    uint2 p;
    p.x = f2h(v.x) | (f2h(v.y) << 16);
    p.y = f2h(v.z) | (f2h(v.w) << 16);
    *(uint2*)(smem + aWriteOff) = p;
  }
  __syncthreads();

  for (int kk = 0; kk < 16; ++kk) {
    const int bb = kk & 1;
    float4 av;
    if (kk < 15) {
      stageB(bb ^ 1, kk + 1);  // async global->LDS into other buffer
      av = *(const float4*)(A + aSrcBase + (size_t)(kk + 1) * 32);
    }
    half8 a0 = *(const half8*)(smem + aReadBase + bb * 4096);
    half8 a1 = *(const half8*)(smem + aReadBase + bb * 4096 + 1024);
#pragma unroll
    for (int n = 0; n < 8; ++n) {
      half8 bf = *(const half8*)(smem + bb * 32768 + bReadBase + n * 1024);
      acc[0][n] = __builtin_amdgcn_mfma_f32_16x16x32_f16(a0, bf, acc[0][n], 0, 0, 0);
      acc[1][n] = __builtin_amdgcn_mfma_f32_16x16x32_f16(a1, bf, acc[1][n], 0, 0, 0);
    }
    if (kk < 15) {
      uint2 p;
      p.x = f2h(av.x) | (f2h(av.y) << 16);
      p.y = f2h(av.z) | (f2h(av.w) << 16);
      *(uint2*)(smem + aWriteOff + (bb ^ 1) * 4096) = p;
    }
    __syncthreads();
  }

  // --- Epilogue: surrogate spike + fused LayerNorm ---
  float bcol[8], lsc[8], lbc[8];
#pragma unroll
  for (int n = 0; n < 8; ++n) {
    const int col = wcol * 128 + n * 16 + l15;
    bcol[n] = bias[col];
    lsc[n]  = lnw[col];
    lbc[n]  = lnb[col];
  }
#pragma unroll
  for (int m = 0; m < 2; ++m)
#pragma unroll
    for (int n = 0; n < 8; ++n)
#pragma unroll
      for (int r = 0; r < 4; ++r) {
        // alpha=exp(-50): v == current in fp32; spike = fast_sigmoid(v - 0.5, 4)
        float x  = acc[m][n][r] + bcol[n] - 0.5f;
        float bx = 4.0f * x;
        acc[m][n][r] = 0.5f * bx / (1.0f + fabsf(bx)) + 0.5f;
      }

  // per-lane partials over this wave's 8 col-fragments, then reduce over 16 lanes
  float rs[2][4], rq[2][4];
#pragma unroll
  for (int m = 0; m < 2; ++m)
#pragma unroll
    for (int r = 0; r < 4; ++r) {
      float s = 0.f, q = 0.f;
#pragma unroll
      for (int n = 0; n < 8; ++n) {
        float v = acc[m][n][r];
        s += v;
        q += v * v;
      }
      rs[m][r] = s;
      rq[m][r] = q;
    }
#pragma unroll
  for (int d = 1; d < 16; d <<= 1) {
#pragma unroll
    for (int m = 0; m < 2; ++m)
#pragma unroll
      for (int r = 0; r < 4; ++r) {
        rs[m][r] += __shfl_xor(rs[m][r], d, 16);
        rq[m][r] += __shfl_xor(rq[m][r], d, 16);
      }
  }

  float* redS = (float*)(smem + 73728);
  float* redQ = (float*)(smem + 74752);
  float* mv   = (float*)(smem + 75776);
  if (l15 == 0) {
#pragma unroll
    for (int m = 0; m < 2; ++m)
#pragma unroll
      for (int r = 0; r < 4; ++r) {
        const int row = wrow * 32 + m * 16 + g * 4 + r;
        redS[row * 4 + wcol] = rs[m][r];
        redQ[row * 4 + wcol] = rq[m][r];
      }
  }
  __syncthreads();
  if (tid < 64) {
    const float S = redS[tid * 4] + redS[tid * 4 + 1] + redS[tid * 4 + 2] + redS[tid * 4 + 3];
    const float Q = redQ[tid * 4] + redQ[tid * 4 + 1] + redQ[tid * 4 + 2] + redQ[tid * 4 + 3];
    const float mean = S * (1.0f / 512.0f);
    const float var  = Q * (1.0f / 512.0f) - mean * mean;
    mv[tid * 2]     = mean;
    mv[tid * 2 + 1] = rsqrtf(var + 1e-6f);
  }
  __syncthreads();

#pragma unroll
  for (int m = 0; m < 2; ++m)
#pragma unroll
    for (int r = 0; r < 4; ++r) {
      const int row  = wrow * 32 + m * 16 + g * 4 + r;
      const float mean = mv[row * 2];
      const float rstd = mv[row * 2 + 1];
      const size_t base = (size_t)(rowBase + row) * 512;
#pragma unroll
      for (int n = 0; n < 8; ++n) {
        const int col = wcol * 128 + n * 16 + l15;
        out[base + col] = (acc[m][n][r] - mean) * rstd * lsc[n] + lbc[n];
      }
    }
}

extern "C" void kernel_launch(void* const* d_in, const int* in_sizes, int n_in,
                              void* d_out, int out_size, void* d_ws, size_t ws_size,
                              hipStream_t stream) {
  const float* spikes = (const float*)d_in[0];
  const float* W      = (const float*)d_in[1];
  const float* b      = (const float*)d_in[2];
  const float* lnw    = (const float*)d_in[3];
  const float* lnb    = (const float*)d_in[4];
  float* out = (float*)d_out;
  unsigned short* Wt = (unsigned short*)d_ws;  // 512*512*2 = 512 KB scratch

  wcvt_kernel<<<dim3(16, 16), dim3(32, 8), 0, stream>>>(W, Wt);
  lif_fused_kernel<<<NBLK, THREADS, 0, stream>>>(spikes, Wt, b, lnw, lnb, out);
}

// Round 2
// 82.362 us; speedup vs baseline: 1.1511x; 1.1511x over previous
//
#include <hip/hip_runtime.h>

#define THREADS 512
#define NBLK 512  // 65536 rows / 128 per block

typedef _Float16 half8 __attribute__((ext_vector_type(8)));
typedef float floatx4 __attribute__((ext_vector_type(4)));

// --- Kernel 1: W [512(k)][512(n)] fp32 -> Wt [512(n)][512(k)] f16 ---
__global__ void wcvt_kernel(const float* __restrict__ W, unsigned short* __restrict__ Wt) {
  __shared__ float tile[32][33];
  const int tx = threadIdx.x, ty = threadIdx.y;
  const int nb = blockIdx.x * 32, kb = blockIdx.y * 32;
#pragma unroll
  for (int i = 0; i < 4; ++i)
    tile[ty + 8 * i][tx] = W[(size_t)(kb + ty + 8 * i) * 512 + nb + tx];
  __syncthreads();
#pragma unroll
  for (int i = 0; i < 4; ++i) {
    union { _Float16 h; unsigned short u; } v;
    v.h = (_Float16)tile[tx][ty + 8 * i];
    Wt[(size_t)(nb + ty + 8 * i) * 512 + kb + tx] = v.u;
  }
}

// --- Kernel 2: fused GEMM + surrogate-sigmoid + rowwise LayerNorm ---
// Block tile: 128 rows x 512 cols. 8 waves = 4 (row) x 2 (col), wave tile 32x256.
// 3-deep all-DMA pipeline, raw s_barrier + counted vmcnt (never 0 in loop).
// LDS (bytes):
//   [0, 49152)       : A fp32, 3 bufs x 16384 (128 rows x 8 slots x 16B, XOR-swizzled)
//   [49152, 147456)  : B f16,  3 bufs x 32768 (512 rows x 4 slots x 16B, XOR-swizzled)
//   reductions alias A region after the K-loop.
#define ABUF 16384
#define BBASE 49152
#define BBUF 32768

__global__ __launch_bounds__(THREADS, 2) void lif_fused_kernel(
    const float* __restrict__ A, const unsigned short* __restrict__ Wt,
    const float* __restrict__ bias, const float* __restrict__ lnw,
    const float* __restrict__ lnb, float* __restrict__ out) {
  __shared__ uint4 smem4[9216];  // 147456 bytes
  unsigned char* smem = (unsigned char*)smem4;

  const int tid  = threadIdx.x;
  const int lane = tid & 63;
  const int wave = tid >> 6;   // 0..7
  const int wrow = wave >> 1;  // 0..3
  const int wcol = wave & 1;   // 0..1
  const int l15  = lane & 15;
  const int g    = lane >> 4;  // 0..3
  const int rowBase = blockIdx.x * 128;

  // Staging source addresses (inverse-swizzled global, linear LDS dest).
  const int bslot = (tid & 3) ^ ((tid >> 3) & 3);
  const int aslot = (tid & 7) ^ ((tid >> 3) & 7);
  const unsigned short* bsrc = Wt + (size_t)(tid >> 2) * 512 + bslot * 8;
  const float* asrc = A + (size_t)(rowBase + (tid >> 3)) * 512 + aslot * 4;

  auto stage = [&](int buf, int kk) {
#pragma unroll
    for (int i = 0; i < 4; ++i) {  // B: 512 rows, 4 x 128 rows
      int off = BBASE + buf * BBUF + i * 8192 + wave * 1024;
      off = __builtin_amdgcn_readfirstlane(off);
      __builtin_amdgcn_global_load_lds(
          (const __attribute__((address_space(1))) void*)(bsrc + (size_t)i * 65536 + kk * 32),
          (__attribute__((address_space(3))) void*)(smem + off), 16, 0, 0);
    }
#pragma unroll
    for (int j = 0; j < 2; ++j) {  // A: 128 rows, 2 x 64 rows (fp32)
      int off = buf * ABUF + j * 8192 + wave * 1024;
      off = __builtin_amdgcn_readfirstlane(off);
      __builtin_amdgcn_global_load_lds(
          (const __attribute__((address_space(1))) void*)(asrc + (size_t)j * 32768 + kk * 32),
          (__attribute__((address_space(3))) void*)(smem + off), 16, 0, 0);
    }
  };

  // Fragment read offsets.
  const int aRowOff = (wrow * 32 + l15) * 128;  // + m*2048 + buf*ABUF
  const int aswz = l15 & 7;
  const int aOff0 = ((g << 1) ^ aswz) << 4;     // logical slot 2g
  const int aOff1 = aOff0 ^ 16;                 // logical slot 2g+1
  const int bRowOff = (wcol * 256 + l15) * 64;  // + n*1024 + buf*BBUF
  const int bsw = (g ^ ((l15 >> 1) & 3)) << 4;

  floatx4 acc[2][16];
#pragma unroll
  for (int m = 0; m < 2; ++m)
#pragma unroll
    for (int n = 0; n < 16; ++n)
      acc[m][n] = (floatx4){0.f, 0.f, 0.f, 0.f};

  stage(0, 0);
  stage(1, 1);

#pragma unroll
  for (int k = 0; k < 16; ++k) {
    if (k < 15) {
      asm volatile("s_waitcnt vmcnt(6)" ::: "memory");  // stage k landed; k+1 in flight
    } else {
      asm volatile("s_waitcnt vmcnt(0)" ::: "memory");
    }
    __builtin_amdgcn_s_barrier();
    __builtin_amdgcn_sched_barrier(0);

    const int buf = k % 3;
    const unsigned char* abase = smem + buf * ABUF + aRowOff;
    half8 a[2];
#pragma unroll
    for (int m = 0; m < 2; ++m) {
      float4 lo = *(const float4*)(abase + m * 2048 + aOff0);
      float4 hi = *(const float4*)(abase + m * 2048 + aOff1);
      half8 t;
      t[0] = (_Float16)lo.x; t[1] = (_Float16)lo.y;
      t[2] = (_Float16)lo.z; t[3] = (_Float16)lo.w;
      t[4] = (_Float16)hi.x; t[5] = (_Float16)hi.y;
      t[6] = (_Float16)hi.z; t[7] = (_Float16)hi.w;
      a[m] = t;
    }
    const unsigned char* bbase = smem + BBASE + buf * BBUF + bRowOff + bsw;
#pragma unroll
    for (int n = 0; n < 16; ++n) {
      half8 bf = *(const half8*)(bbase + n * 1024);
      acc[0][n] = __builtin_amdgcn_mfma_f32_16x16x32_f16(a[0], bf, acc[0][n], 0, 0, 0);
      acc[1][n] = __builtin_amdgcn_mfma_f32_16x16x32_f16(a[1], bf, acc[1][n], 0, 0, 0);
    }

    if (k < 14) stage((k + 2) % 3, k + 2);
  }
  __syncthreads();

  // --- Epilogue: bias + surrogate spike + fused LayerNorm ---
  float bcol[16], lsc[16], lbc[16];
#pragma unroll
  for (int n = 0; n < 16; ++n) {
    const int col = wcol * 256 + n * 16 + l15;
    bcol[n] = bias[col];
    lsc[n]  = lnw[col];
    lbc[n]  = lnb[col];
  }
#pragma unroll
  for (int m = 0; m < 2; ++m)
#pragma unroll
    for (int n = 0; n < 16; ++n)
#pragma unroll
      for (int r = 0; r < 4; ++r) {
        // alpha=exp(-50): v == current in fp32; spike = fast_sigmoid(v - 0.5, 4)
        float x  = acc[m][n][r] + bcol[n] - 0.5f;
        float bx = 4.0f * x;
        acc[m][n][r] = 0.5f * bx / (1.0f + fabsf(bx)) + 0.5f;
      }

  float rs[2][4], rq[2][4];
#pragma unroll
  for (int m = 0; m < 2; ++m)
#pragma unroll
    for (int r = 0; r < 4; ++r) {
      float s = 0.f, q = 0.f;
#pragma unroll
      for (int n = 0; n < 16; ++n) {
        float v = acc[m][n][r];
        s += v;
        q += v * v;
      }
      rs[m][r] = s;
      rq[m][r] = q;
    }
#pragma unroll
  for (int d = 1; d < 16; d <<= 1) {
#pragma unroll
    for (int m = 0; m < 2; ++m)
#pragma unroll
      for (int r = 0; r < 4; ++r) {
        rs[m][r] += __shfl_xor(rs[m][r], d, 16);
        rq[m][r] += __shfl_xor(rq[m][r], d, 16);
      }
  }

  float* redS = (float*)smem4;   // [128][2]
  float* redQ = redS + 256;      // [128][2]
  float* mv   = redQ + 256;      // [128][2]
  if (l15 == 0) {
#pragma unroll
    for (int m = 0; m < 2; ++m)
#pragma unroll
      for (int r = 0; r < 4; ++r) {
        const int row = wrow * 32 + m * 16 + g * 4 + r;
        redS[row * 2 + wcol] = rs[m][r];
        redQ[row * 2 + wcol] = rq[m][r];
      }
  }
  __syncthreads();
  if (tid < 128) {
    const float S = redS[tid * 2] + redS[tid * 2 + 1];
    const float Q = redQ[tid * 2] + redQ[tid * 2 + 1];
    const float mean = S * (1.0f / 512.0f);
    const float var  = Q * (1.0f / 512.0f) - mean * mean;
    mv[tid * 2]     = mean;
    mv[tid * 2 + 1] = rsqrtf(var + 1e-6f);
  }
  __syncthreads();

#pragma unroll
  for (int m = 0; m < 2; ++m)
#pragma unroll
    for (int r = 0; r < 4; ++r) {
      const int row  = wrow * 32 + m * 16 + g * 4 + r;
      const float mean = mv[row * 2];
      const float rstd = mv[row * 2 + 1];
      const size_t base = (size_t)(rowBase + row) * 512;
#pragma unroll
      for (int n = 0; n < 16; ++n) {
        const int col = wcol * 256 + n * 16 + l15;
        out[base + col] = (acc[m][n][r] - mean) * rstd * lsc[n] + lbc[n];
      }
    }
}

extern "C" void kernel_launch(void* const* d_in, const int* in_sizes, int n_in,
                              void* d_out, int out_size, void* d_ws, size_t ws_size,
                              hipStream_t stream) {
  const float* spikes = (const float*)d_in[0];
  const float* W      = (const float*)d_in[1];
  const float* b      = (const float*)d_in[2];
  const float* lnw    = (const float*)d_in[3];
  const float* lnb    = (const float*)d_in[4];
  float* out = (float*)d_out;
  unsigned short* Wt = (unsigned short*)d_ws;  // 512*512*2 = 512 KB scratch

  wcvt_kernel<<<dim3(16, 16), dim3(32, 8), 0, stream>>>(W, Wt);
  lif_fused_kernel<<<NBLK, THREADS, 0, stream>>>(spikes, Wt, b, lnw, lnb, out);
}